// Round 4
// baseline (164.522 us; speedup 1.0000x reference)
//
#include <hip/hip_runtime.h>

#define BATCH 16384
#define DIM 128

typedef __attribute__((ext_vector_type(8))) short short8;
typedef __attribute__((ext_vector_type(4))) float floatx4;

__device__ __forceinline__ ushort f2bf(float f) {
    union { float f; uint u; } c; c.f = f;
    return (ushort)((c.u + 0x7FFFu + ((c.u >> 16) & 1u)) >> 16);
}
__device__ __forceinline__ float bf2f(ushort h) {
    union { uint u; float f; } c; c.u = ((uint)h) << 16;
    return c.f;
}
__device__ __forceinline__ ushort4 f4_to_bf4(float4 v) {
    return make_ushort4(f2bf(v.x), f2bf(v.y), f2bf(v.z), f2bf(v.w));
}

// Fragment-major slot index, 256-col buffers (KT=8 fixed):
// element (m,k) -> 16B slot ((m>>4)*8 + (k>>5))*64 + ((k>>3)&3)*16 + (m&15),
// byte offset (k&7)*2.  Wave A-frag (mt,kf) = slots [(mt*8+kf)*64 + lane]:
// lane-contiguous 16B reads, zero bank conflicts.
__device__ __forceinline__ int slot_idx(int m, int k) {
    return (((m >> 4) * 8 + (k >> 5)) << 6) + (((k >> 3) & 3) << 4) + (m & 15);
}

// ---------------------------------------------------------------------------
// Weight convert: fp32 [K][N] -> bf16 fragment-major [frag(nt,kf)][lane].
// One wave per 16x32 fragment; lane(q,r) holds W[k0+q*8+j][n0+r], j=0..7.
// Frag counts: Wu 8x4=32, W1 16x8=128, W2 8x8=64 -> 224 waves = 56 blocks.
// ---------------------------------------------------------------------------
__global__ __launch_bounds__(256) void convert_kernel(
    const float* __restrict__ Wu, const float* __restrict__ W1,
    const float* __restrict__ W2, short8* __restrict__ WF)
{
    const int f    = blockIdx.x * 4 + (threadIdx.x >> 6);
    const int lane = threadIdx.x & 63;
    const int q = lane >> 4, r = lane & 15;
    const float* W; int N, nt, kf, fl; short8* dst;
    if (f < 32)       { W = Wu; N = 128; fl = f;       nt = fl >> 2; kf = fl & 3; dst = WF;         }
    else if (f < 160) { W = W1; N = 256; fl = f - 32;  nt = fl >> 3; kf = fl & 7; dst = WF + 2048;  }
    else              { W = W2; N = 128; fl = f - 160; nt = fl >> 3; kf = fl & 7; dst = WF + 10240; }
    const int n = nt * 16 + r, k0 = kf * 32 + q * 8;
    short8 v;
    #pragma unroll
    for (int j = 0; j < 8; ++j)
        v[j] = (short)f2bf(W[(size_t)(k0 + j) * N + n]);
    dst[fl * 64 + lane] = v;
}

// ---------------------------------------------------------------------------
// One MFMA layer on fragment-major 256-wide buffers (SKT=DKT=8).
// KF = K/32 source frag cols, NT = N/16 output col tiles, 4 m-tiles (64 rows).
// A-frags register-cached across the nt loop.
// ---------------------------------------------------------------------------
template<int KF, int NT>
__device__ __forceinline__ void layer_mfma(
    const short8* __restrict__ src, const short8* __restrict__ WF,
    const float* __restrict__ bias, ushort* __restrict__ dst, int tid)
{
    const int wave = tid >> 6, lane = tid & 63;
    const int q = lane >> 4, r = lane & 15;
    short8 a[4][KF];
    #pragma unroll
    for (int mt = 0; mt < 4; ++mt)
        #pragma unroll
        for (int kf = 0; kf < KF; ++kf)
            a[mt][kf] = src[(mt * 8 + kf) * 64 + lane];
    #pragma unroll
    for (int nt = wave; nt < NT; nt += 4) {
        const int col = nt * 16 + r;
        short8 b[KF];
        #pragma unroll
        for (int kf = 0; kf < KF; ++kf)
            b[kf] = WF[(nt * KF + kf) * 64 + lane];
        const float bs = bias[col];
        const int kc = col >> 5, qc = (col >> 3) & 3, e = col & 7;
        #pragma unroll
        for (int mt = 0; mt < 4; ++mt) {
            floatx4 acc = {0.f, 0.f, 0.f, 0.f};
            #pragma unroll
            for (int kf = 0; kf < KF; ++kf)
                acc = __builtin_amdgcn_mfma_f32_16x16x32_bf16(a[mt][kf], b[kf], acc, 0, 0, 0);
            #pragma unroll
            for (int rr = 0; rr < 4; ++rr) {
                const int rlow = q * 4 + rr;   // row & 15
                dst[(size_t)((((mt * 8 + kc) << 6) + (qc << 4) + rlow) * 8 + e)] =
                    f2bf(fmaxf(acc[rr] + bs, 0.f));
            }
        }
    }
}

// ---------------------------------------------------------------------------
// Fully fused model: 64 rows/block, 256 blocks, 256 threads.
// sA/sB ping-pong, both [64 rows][256 cols] frag-major (32 KB each).
// item_c lives in sA kf-slots 4..7; user MLP ping-pongs kf-slots 0..3.
// ---------------------------------------------------------------------------
__global__ __launch_bounds__(256, 2) void fused_kernel(
    const int* __restrict__ user_ids, const int* __restrict__ item_ids,
    const float* __restrict__ rec_target,
    const float* __restrict__ user_tbl, const float* __restrict__ item_tbl,
    const float* __restrict__ entity_tbl,
    const float* __restrict__ w_vv, const float* __restrict__ w_ev,
    const float* __restrict__ w_ve, const float* __restrict__ w_ee,
    const float* __restrict__ bias_v, const float* __restrict__ bias_e,
    const short8* __restrict__ WF, const float* __restrict__ bu,
    const float* __restrict__ b1, const float* __restrict__ b2,
    const float* __restrict__ W3, const float* __restrict__ b3,
    float* __restrict__ out)
{
    __shared__ short8 sA[2048];
    __shared__ short8 sB[2048];

    const int r0  = blockIdx.x * 64;
    const int tid = threadIdx.x;
    const int row = tid >> 2, l = tid & 3;   // 4 threads per row, 32 cols each

    if (tid < 64) out[BATCH + r0 + tid] = rec_target[r0 + tid];

    // --- gather user rows -> bf16 -> sA kf 0..3 ---
    {
        const int uid = user_ids[r0 + row];
        const float4* src = (const float4*)(user_tbl + (size_t)uid * DIM + l * 32);
        ushort* p = (ushort*)sA;
        #pragma unroll
        for (int i = 0; i < 8; ++i) {
            const int col = l * 32 + i * 4;
            *(ushort4*)&p[slot_idx(row, col) * 8 + (col & 7)] = f4_to_bf4(src[i]);
        }
    }

    // --- cross-compress (2 layers, fp32) -> sA kf 4..7 (item_c) ---
    {
        const int id = item_ids[r0 + row];
        const float4* ip = (const float4*)(item_tbl   + (size_t)id * DIM + l * 32);
        const float4* hp = (const float4*)(entity_tbl + (size_t)id * DIM + l * 32);
        float4 it4[8], hd4[8];
        #pragma unroll
        for (int i = 0; i < 8; ++i) { it4[i] = ip[i]; hd4[i] = hp[i]; }
        const float bv = bias_v[0], be = bias_e[0];
        #pragma unroll
        for (int lay = 0; lay < 2; ++lay) {
            float hv = 0.f, iv = 0.f, he = 0.f, ie = 0.f;
            #pragma unroll
            for (int i = 0; i < 8; ++i) {
                float4 wvv = ((const float4*)w_vv)[l * 8 + i];
                float4 wev = ((const float4*)w_ev)[l * 8 + i];
                float4 wve = ((const float4*)w_ve)[l * 8 + i];
                float4 wee = ((const float4*)w_ee)[l * 8 + i];
                hv += hd4[i].x * wvv.x + hd4[i].y * wvv.y + hd4[i].z * wvv.z + hd4[i].w * wvv.w;
                iv += it4[i].x * wev.x + it4[i].y * wev.y + it4[i].z * wev.z + it4[i].w * wev.w;
                he += hd4[i].x * wve.x + hd4[i].y * wve.y + hd4[i].z * wve.z + hd4[i].w * wve.w;
                ie += it4[i].x * wee.x + it4[i].y * wee.y + it4[i].z * wee.z + it4[i].w * wee.w;
            }
            hv += __shfl_xor(hv, 1); hv += __shfl_xor(hv, 2);
            iv += __shfl_xor(iv, 1); iv += __shfl_xor(iv, 2);
            he += __shfl_xor(he, 1); he += __shfl_xor(he, 2);
            ie += __shfl_xor(ie, 1); ie += __shfl_xor(ie, 2);
            #pragma unroll
            for (int i = 0; i < 8; ++i) {
                float4 t = it4[i], h = hd4[i];
                it4[i].x = t.x * hv + h.x * iv + bv;  hd4[i].x = t.x * he + h.x * ie + be;
                it4[i].y = t.y * hv + h.y * iv + bv;  hd4[i].y = t.y * he + h.y * ie + be;
                it4[i].z = t.z * hv + h.z * iv + bv;  hd4[i].z = t.z * he + h.z * ie + be;
                it4[i].w = t.w * hv + h.w * iv + bv;  hd4[i].w = t.w * he + h.w * ie + be;
            }
        }
        ushort* p = (ushort*)sA;
        #pragma unroll
        for (int i = 0; i < 8; ++i) {
            const int col = 128 + l * 32 + i * 4;
            *(ushort4*)&p[slot_idx(row, col) * 8 + (col & 7)] = f4_to_bf4(it4[i]);
        }
    }
    __syncthreads();

    layer_mfma<4, 8>(sA, WF,          bu, (ushort*)sB, tid);   // user L1: sA kf0..3 -> sB kf0..3
    __syncthreads();
    layer_mfma<4, 8>(sB, WF,          bu, (ushort*)sA, tid);   // user L2: -> sA kf0..3 (item_c kf4..7 intact)
    __syncthreads();
    layer_mfma<8, 16>(sA, WF + 2048,  b1, (ushort*)sB, tid);   // mlp1: high(sA) -> sB
    __syncthreads();
    layer_mfma<8, 8>(sB, WF + 10240,  b2, (ushort*)sA, tid);   // mlp2: sB -> sA kf0..3
    __syncthreads();

    // --- mlp3: per-row dot with W3[128] + b3, relu ---
    {
        float p = 0.f;
        #pragma unroll
        for (int i = 0; i < 4; ++i) {
            const int c8 = l * 4 + i;  // 8-col group, 0..15
            short8 h = sA[(((row >> 4) * 8 + (c8 >> 2)) << 6) + ((c8 & 3) << 4) + (row & 15)];
            float4 w0 = ((const float4*)W3)[c8 * 2];
            float4 w1 = ((const float4*)W3)[c8 * 2 + 1];
            p += bf2f((ushort)h[0]) * w0.x + bf2f((ushort)h[1]) * w0.y
               + bf2f((ushort)h[2]) * w0.z + bf2f((ushort)h[3]) * w0.w
               + bf2f((ushort)h[4]) * w1.x + bf2f((ushort)h[5]) * w1.y
               + bf2f((ushort)h[6]) * w1.z + bf2f((ushort)h[7]) * w1.w;
        }
        p += __shfl_xor(p, 1); p += __shfl_xor(p, 2);
        if (l == 0) out[r0 + row] = fmaxf(p + b3[0], 0.f);
    }
}

// ---------------------------------------------------------------------------
extern "C" void kernel_launch(void* const* d_in, const int* in_sizes, int n_in,
                              void* d_out, int out_size, void* d_ws, size_t ws_size,
                              hipStream_t stream)
{
    const int*   user_ids   = (const int*)  d_in[0];
    const int*   item_ids   = (const int*)  d_in[1];
    const float* rec_target = (const float*)d_in[2];
    const float* user_tbl   = (const float*)d_in[3];
    const float* item_tbl   = (const float*)d_in[4];
    const float* entity_tbl = (const float*)d_in[5];
    const float* w_vv       = (const float*)d_in[6];
    const float* w_ev       = (const float*)d_in[7];
    const float* w_ve       = (const float*)d_in[8];
    const float* w_ee       = (const float*)d_in[9];
    const float* bias_v     = (const float*)d_in[10];
    const float* bias_e     = (const float*)d_in[11];
    const float* Wu         = (const float*)d_in[12];
    const float* bu         = (const float*)d_in[13];
    const float* W1         = (const float*)d_in[14];
    const float* b1         = (const float*)d_in[15];
    const float* W2         = (const float*)d_in[16];
    const float* b2         = (const float*)d_in[17];
    const float* W3         = (const float*)d_in[18];
    const float* b3         = (const float*)d_in[19];
    float* out = (float*)d_out;

    short8* WF = (short8*)d_ws;   // Wu frags [0,2048) | W1 [2048,10240) | W2 [10240,14336)

    convert_kernel<<<56, 256, 0, stream>>>(Wu, W1, W2, WF);
    fused_kernel<<<BATCH / 64, 256, 0, stream>>>(
        user_ids, item_ids, rec_target, user_tbl, item_tbl, entity_tbl,
        w_vv, w_ev, w_ve, w_ee, bias_v, bias_e,
        WF, bu, b1, b2, W3, b3, out);
}

// Round 5
// 155.531 us; speedup vs baseline: 1.0578x; 1.0578x over previous
//
#include <hip/hip_runtime.h>

#define BATCH 16384
#define DIM 128

typedef __attribute__((ext_vector_type(8))) short short8;
typedef __attribute__((ext_vector_type(4))) float floatx4;

__device__ __forceinline__ ushort f2bf(float f) {
    union { float f; uint u; } c; c.f = f;
    return (ushort)((c.u + 0x7FFFu + ((c.u >> 16) & 1u)) >> 16);
}
__device__ __forceinline__ float bf2f(ushort h) {
    union { uint u; float f; } c; c.u = ((uint)h) << 16;
    return c.f;
}
__device__ __forceinline__ ushort4 f4_to_bf4(float4 v) {
    return make_ushort4(f2bf(v.x), f2bf(v.y), f2bf(v.z), f2bf(v.w));
}

// Fragment-major slot index for a 32-row activation buffer with KT 32-col
// fragment groups: element (m,k) -> 16B slot
//   ((m>>4)*KT + (k>>5))*64 + ((k>>3)&3)*16 + (m&15),  byte offset (k&7)*2.
// A wave's MFMA A-fragment (mt,kf) = slots [(mt*KT+kf)*64 + lane]: lane-
// contiguous 16B reads, zero bank conflicts.
__device__ __forceinline__ int slot_idx(int KT, int m, int k) {
    return (((m >> 4) * KT + (k >> 5)) << 6) + (((k >> 3) & 3) << 4) + (m & 15);
}

// ---------------------------------------------------------------------------
// Weight convert: fp32 [K][N] -> bf16 fragment-major [frag(nt,kf)][lane].
// One wave per 16x32 fragment; lane(q,r) holds W[k0+q*8+j][n0+r], j=0..7.
// Frag counts: Wu 8x4=32, W1 16x8=128, W2 8x8=64 -> 224 waves = 56 blocks.
// ---------------------------------------------------------------------------
__global__ __launch_bounds__(256) void convert_kernel(
    const float* __restrict__ Wu, const float* __restrict__ W1,
    const float* __restrict__ W2, short8* __restrict__ WF)
{
    const int f    = blockIdx.x * 4 + (threadIdx.x >> 6);
    const int lane = threadIdx.x & 63;
    const int q = lane >> 4, r = lane & 15;
    const float* W; int N, nt, kf, fl; short8* dst;
    if (f < 32)       { W = Wu; N = 128; fl = f;       nt = fl >> 2; kf = fl & 3; dst = WF;         }
    else if (f < 160) { W = W1; N = 256; fl = f - 32;  nt = fl >> 3; kf = fl & 7; dst = WF + 2048;  }
    else              { W = W2; N = 128; fl = f - 160; nt = fl >> 3; kf = fl & 7; dst = WF + 10240; }
    const int n = nt * 16 + r, k0 = kf * 32 + q * 8;
    short8 v;
    #pragma unroll
    for (int j = 0; j < 8; ++j)
        v[j] = (short)f2bf(W[(size_t)(k0 + j) * N + n]);
    dst[fl * 64 + lane] = v;
}

// ---------------------------------------------------------------------------
// One MFMA layer on fragment-major buffers (32 rows).
// KF = K/32 (src frag cols), NT = N/16 (output col tiles), DKT = dstN/32.
// A-frags register-cached across the nt loop.
// ---------------------------------------------------------------------------
template<int KF, int NT, int DKT>
__device__ __forceinline__ void layer_mfma(
    const short8* __restrict__ src, const short8* __restrict__ WF,
    const float* __restrict__ bias, ushort* __restrict__ dst, int tid)
{
    const int wave = tid >> 6, lane = tid & 63;
    const int q = lane >> 4, r = lane & 15;
    short8 a[2][KF];
    #pragma unroll
    for (int mt = 0; mt < 2; ++mt)
        #pragma unroll
        for (int kf = 0; kf < KF; ++kf)
            a[mt][kf] = src[(mt * KF + kf) * 64 + lane];
    #pragma unroll
    for (int nt = wave; nt < NT; nt += 4) {
        const int col = nt * 16 + r;
        short8 b[KF];
        #pragma unroll
        for (int kf = 0; kf < KF; ++kf)
            b[kf] = WF[(nt * KF + kf) * 64 + lane];
        const float bs = bias[col];
        const int kc = col >> 5, qc = (col >> 3) & 3, e = col & 7;
        #pragma unroll
        for (int mt = 0; mt < 2; ++mt) {
            floatx4 acc = {0.f, 0.f, 0.f, 0.f};
            #pragma unroll
            for (int kf = 0; kf < KF; ++kf)
                acc = __builtin_amdgcn_mfma_f32_16x16x32_bf16(a[mt][kf], b[kf], acc, 0, 0, 0);
            #pragma unroll
            for (int rr = 0; rr < 4; ++rr) {
                const int rlow = q * 4 + rr;   // row & 15
                dst[(size_t)((((mt * DKT + kc) << 6) + (qc << 4) + rlow) * 8 + e)] =
                    f2bf(fmaxf(acc[rr] + bs, 0.f));
            }
        }
    }
}

// ---------------------------------------------------------------------------
// Fully fused model: 32 rows/block, 512 blocks, 256 threads.
// Wu B-frags (shared by user L1 and L2) are prefetched at kernel start and
// register-resident across both layers.
// ---------------------------------------------------------------------------
__global__ __launch_bounds__(256) void fused_kernel(
    const int* __restrict__ user_ids, const int* __restrict__ item_ids,
    const float* __restrict__ rec_target,
    const float* __restrict__ user_tbl, const float* __restrict__ item_tbl,
    const float* __restrict__ entity_tbl,
    const float* __restrict__ w_vv, const float* __restrict__ w_ev,
    const float* __restrict__ w_ve, const float* __restrict__ w_ee,
    const float* __restrict__ bias_v, const float* __restrict__ bias_e,
    const short8* __restrict__ WF, const float* __restrict__ bu,
    const float* __restrict__ b1, const float* __restrict__ b2,
    const float* __restrict__ W3, const float* __restrict__ b3,
    float* __restrict__ out)
{
    __shared__ short8 sU0[512];    // user in   [32][128] frag-major (KT=4)
    __shared__ short8 sU1[512];    // user mid  (KT=4)
    __shared__ short8 sHI[1024];   // high      [32][256] (KT=8)
    __shared__ short8 sH1[1024];   // mlp1 out  (KT=8)
    __shared__ short8 sH2[512];    // mlp2 out  (KT=4)

    const int r0   = blockIdx.x * 32;
    const int tid  = threadIdx.x;
    const int wave = tid >> 6, lane = tid & 63;
    const int q    = lane >> 4, r = lane & 15;
    const int row  = tid >> 3, l = tid & 7;   // 8 threads per row (staging)

    // --- prefetch Wu B-frags: nt = wave, wave+4; identical for L1 and L2 ---
    short8 bw[2][4];
    #pragma unroll
    for (int i = 0; i < 2; ++i) {
        const int nt = wave + i * 4;
        #pragma unroll
        for (int kf = 0; kf < 4; ++kf)
            bw[i][kf] = WF[(nt * 4 + kf) * 64 + lane];
    }

    if (tid < 32) out[BATCH + r0 + tid] = rec_target[r0 + tid];

    // --- gather user rows -> bf16 -> sU0 (frag-major) ---
    {
        const int uid = user_ids[r0 + row];
        const float4* src = (const float4*)(user_tbl + (size_t)uid * DIM + l * 16);
        ushort* p = (ushort*)sU0;
        #pragma unroll
        for (int i = 0; i < 4; ++i) {
            const int col = l * 16 + i * 4;
            *(ushort4*)&p[slot_idx(4, row, col) * 8 + (col & 7)] = f4_to_bf4(src[i]);
        }
    }

    // --- cross-compress (2 layers, fp32) -> sHI cols 128..255 ---
    {
        const int id = item_ids[r0 + row];
        const float4* ip = (const float4*)(item_tbl   + (size_t)id * DIM + l * 16);
        const float4* hp = (const float4*)(entity_tbl + (size_t)id * DIM + l * 16);
        float4 it4[4], hd4[4];
        #pragma unroll
        for (int i = 0; i < 4; ++i) { it4[i] = ip[i]; hd4[i] = hp[i]; }
        const float bv = bias_v[0], be = bias_e[0];
        #pragma unroll
        for (int lay = 0; lay < 2; ++lay) {
            float hv = 0.f, iv = 0.f, he = 0.f, ie = 0.f;
            #pragma unroll
            for (int i = 0; i < 4; ++i) {
                float4 wvv = ((const float4*)w_vv)[l * 4 + i];
                float4 wev = ((const float4*)w_ev)[l * 4 + i];
                float4 wve = ((const float4*)w_ve)[l * 4 + i];
                float4 wee = ((const float4*)w_ee)[l * 4 + i];
                hv += hd4[i].x * wvv.x + hd4[i].y * wvv.y + hd4[i].z * wvv.z + hd4[i].w * wvv.w;
                iv += it4[i].x * wev.x + it4[i].y * wev.y + it4[i].z * wev.z + it4[i].w * wev.w;
                he += hd4[i].x * wve.x + hd4[i].y * wve.y + hd4[i].z * wve.z + hd4[i].w * wve.w;
                ie += it4[i].x * wee.x + it4[i].y * wee.y + it4[i].z * wee.z + it4[i].w * wee.w;
            }
            hv += __shfl_xor(hv, 1); hv += __shfl_xor(hv, 2); hv += __shfl_xor(hv, 4);
            iv += __shfl_xor(iv, 1); iv += __shfl_xor(iv, 2); iv += __shfl_xor(iv, 4);
            he += __shfl_xor(he, 1); he += __shfl_xor(he, 2); he += __shfl_xor(he, 4);
            ie += __shfl_xor(ie, 1); ie += __shfl_xor(ie, 2); ie += __shfl_xor(ie, 4);
            #pragma unroll
            for (int i = 0; i < 4; ++i) {
                float4 t = it4[i], h = hd4[i];
                it4[i].x = t.x * hv + h.x * iv + bv;  hd4[i].x = t.x * he + h.x * ie + be;
                it4[i].y = t.y * hv + h.y * iv + bv;  hd4[i].y = t.y * he + h.y * ie + be;
                it4[i].z = t.z * hv + h.z * iv + bv;  hd4[i].z = t.z * he + h.z * ie + be;
                it4[i].w = t.w * hv + h.w * iv + bv;  hd4[i].w = t.w * he + h.w * ie + be;
            }
        }
        ushort* p = (ushort*)sHI;
        #pragma unroll
        for (int i = 0; i < 4; ++i) {
            const int col = 128 + l * 16 + i * 4;
            *(ushort4*)&p[slot_idx(8, row, col) * 8 + (col & 7)] = f4_to_bf4(it4[i]);
        }
    }
    __syncthreads();

    // --- user L1: sU0 -> sU1 (DKT=4), using prefetched bw ---
    {
        short8 a[2][4];
        #pragma unroll
        for (int mt = 0; mt < 2; ++mt)
            #pragma unroll
            for (int kf = 0; kf < 4; ++kf)
                a[mt][kf] = sU0[(mt * 4 + kf) * 64 + lane];
        #pragma unroll
        for (int i = 0; i < 2; ++i) {
            const int col = (wave + i * 4) * 16 + r;
            const float bs = bu[col];
            const int kc = col >> 5, qc = (col >> 3) & 3, e = col & 7;
            #pragma unroll
            for (int mt = 0; mt < 2; ++mt) {
                floatx4 acc = {0.f, 0.f, 0.f, 0.f};
                #pragma unroll
                for (int kf = 0; kf < 4; ++kf)
                    acc = __builtin_amdgcn_mfma_f32_16x16x32_bf16(a[mt][kf], bw[i][kf], acc, 0, 0, 0);
                ushort* dst = (ushort*)sU1;
                #pragma unroll
                for (int rr = 0; rr < 4; ++rr)
                    dst[(((mt * 4 + kc) << 6) + (qc << 4) + q * 4 + rr) * 8 + e] =
                        f2bf(fmaxf(acc[rr] + bs, 0.f));
            }
        }
    }
    __syncthreads();

    // --- user L2: sU1 -> sHI cols 0..127 (DKT=8), same bw ---
    {
        short8 a[2][4];
        #pragma unroll
        for (int mt = 0; mt < 2; ++mt)
            #pragma unroll
            for (int kf = 0; kf < 4; ++kf)
                a[mt][kf] = sU1[(mt * 4 + kf) * 64 + lane];
        #pragma unroll
        for (int i = 0; i < 2; ++i) {
            const int col = (wave + i * 4) * 16 + r;
            const float bs = bu[col];
            const int kc = col >> 5, qc = (col >> 3) & 3, e = col & 7;
            #pragma unroll
            for (int mt = 0; mt < 2; ++mt) {
                floatx4 acc = {0.f, 0.f, 0.f, 0.f};
                #pragma unroll
                for (int kf = 0; kf < 4; ++kf)
                    acc = __builtin_amdgcn_mfma_f32_16x16x32_bf16(a[mt][kf], bw[i][kf], acc, 0, 0, 0);
                ushort* dst = (ushort*)sHI;
                #pragma unroll
                for (int rr = 0; rr < 4; ++rr)
                    dst[(((mt * 8 + kc) << 6) + (qc << 4) + q * 4 + rr) * 8 + e] =
                        f2bf(fmaxf(acc[rr] + bs, 0.f));
            }
        }
    }
    __syncthreads();

    layer_mfma<8, 16, 8>(sHI, WF + 2048,  b1, (ushort*)sH1, tid);   // mlp1
    __syncthreads();
    layer_mfma<8, 8, 4>(sH1, WF + 10240,  b2, (ushort*)sH2, tid);   // mlp2
    __syncthreads();

    // --- mlp3: per-row dot with W3[128] + b3, relu ---
    {
        float p = 0.f;
        #pragma unroll
        for (int i = 0; i < 2; ++i) {
            const int c8 = l * 2 + i;
            short8 h = sH2[(((row >> 4) * 4 + (c8 >> 2)) << 6) + ((c8 & 3) << 4) + (row & 15)];
            float4 w0 = ((const float4*)W3)[c8 * 2];
            float4 w1 = ((const float4*)W3)[c8 * 2 + 1];
            p += bf2f((ushort)h[0]) * w0.x + bf2f((ushort)h[1]) * w0.y
               + bf2f((ushort)h[2]) * w0.z + bf2f((ushort)h[3]) * w0.w
               + bf2f((ushort)h[4]) * w1.x + bf2f((ushort)h[5]) * w1.y
               + bf2f((ushort)h[6]) * w1.z + bf2f((ushort)h[7]) * w1.w;
        }
        p += __shfl_xor(p, 1); p += __shfl_xor(p, 2); p += __shfl_xor(p, 4);
        if (l == 0) out[r0 + row] = fmaxf(p + b3[0], 0.f);
    }
}

// ---------------------------------------------------------------------------
extern "C" void kernel_launch(void* const* d_in, const int* in_sizes, int n_in,
                              void* d_out, int out_size, void* d_ws, size_t ws_size,
                              hipStream_t stream)
{
    const int*   user_ids   = (const int*)  d_in[0];
    const int*   item_ids   = (const int*)  d_in[1];
    const float* rec_target = (const float*)d_in[2];
    const float* user_tbl   = (const float*)d_in[3];
    const float* item_tbl   = (const float*)d_in[4];
    const float* entity_tbl = (const float*)d_in[5];
    const float* w_vv       = (const float*)d_in[6];
    const float* w_ev       = (const float*)d_in[7];
    const float* w_ve       = (const float*)d_in[8];
    const float* w_ee       = (const float*)d_in[9];
    const float* bias_v     = (const float*)d_in[10];
    const float* bias_e     = (const float*)d_in[11];
    const float* Wu         = (const float*)d_in[12];
    const float* bu         = (const float*)d_in[13];
    const float* W1         = (const float*)d_in[14];
    const float* b1         = (const float*)d_in[15];
    const float* W2         = (const float*)d_in[16];
    const float* b2         = (const float*)d_in[17];
    const float* W3         = (const float*)d_in[18];
    const float* b3         = (const float*)d_in[19];
    float* out = (float*)d_out;

    short8* WF = (short8*)d_ws;   // Wu frags [0,2048) | W1 [2048,10240) | W2 [10240,14336)

    convert_kernel<<<56, 256, 0, stream>>>(Wu, W1, W2, WF);
    fused_kernel<<<BATCH / 32, 256, 0, stream>>>(
        user_ids, item_ids, rec_target, user_tbl, item_tbl, entity_tbl,
        w_vv, w_ev, w_ve, w_ee, bias_v, bias_e,
        WF, bu, b1, b2, W3, b3, out);
}